// Round 14
// baseline (843.927 us; speedup 1.0000x reference)
//
#include <hip/hip_runtime.h>
#include <hip/hip_bf16.h>

// Problem constants (fixed by reference)
#define SEQ    2048
#define BATCH  2
#define MROWS  (SEQ*BATCH)    // 4096
#define EMBED  1024
#define KCTX   3
#define XDIM   (KCTX*EMBED)   // 3072
#define VOCAB  50257
#define VPAD2  50432          // Wout^T rows allocated (394*128, zero-filled tail)
#define GK     1024           // K of the logits GEMM
#define NWG3   12608          // 32 m-blocks x 394 n-blocks = 8 x 1576

using u16 = unsigned short;
typedef __attribute__((ext_vector_type(8))) short   frag_ab;  // 8 bf16
typedef __attribute__((ext_vector_type(4))) float   frag_cd;  // 4 f32

__device__ __forceinline__ u16 f2bf(float f) {
  union { float f; unsigned u; } v; v.f = f;
  unsigned r = v.u + 0x7fffu + ((v.u >> 16) & 1u);
  return (u16)(r >> 16);
}

__device__ __forceinline__ void gload16(const u16* g, const u16* l) {
  __builtin_amdgcn_global_load_lds((const __attribute__((address_space(1))) void*)g,
                                   (__attribute__((address_space(3))) void*)l, 16, 0, 0);
}

// ---------------------------------------------------------------------------
// Gather: XB[r][i*1024+c] = bf16(E[tok(r,i)][c]); r = s*BATCH+b
// ---------------------------------------------------------------------------
__global__ void gather_x(const int* __restrict__ tokens,
                         const float* __restrict__ E,
                         u16* __restrict__ XB) {
  const int r = blockIdx.x;
  const int s = r >> 1, b = r & 1;
  #pragma unroll
  for (int i = 0; i < KCTX; ++i) {
    int t = s + i - (KCTX - 1);
    int tok = (t >= 0) ? tokens[t * BATCH + b] : 0;
    const float* src = &E[(size_t)tok * EMBED];
    u16* dst = &XB[(size_t)r * XDIM + i * EMBED];
    int c = threadIdx.x * 4;
    float4 v = *(const float4*)&src[c];
    u16 o[4] = { f2bf(v.x), f2bf(v.y), f2bf(v.z), f2bf(v.w) };
    *(ulong1*)&dst[c] = *(ulong1*)o;
  }
}

// ---------------------------------------------------------------------------
// Transpose + f32->bf16: W (K x N) -> WT (Npad x K). n >= N writes 0.
// ---------------------------------------------------------------------------
__global__ void transpose_cvt(const float* __restrict__ W,
                              u16* __restrict__ WT,
                              int K, int N) {
  __shared__ float tile[32][33];
  const int nb = blockIdx.x * 32, kb = blockIdx.y * 32;
  const int tx = threadIdx.x & 31, ty = threadIdx.x >> 5;
  #pragma unroll
  for (int i = 0; i < 32; i += 8) {
    int k = kb + ty + i, n = nb + tx;
    tile[ty + i][tx] = (n < N) ? W[(size_t)k * N + n] : 0.f;
  }
  __syncthreads();
  #pragma unroll
  for (int i = 0; i < 32; i += 8) {
    int n = nb + ty + i, k = kb + tx;
    WT[(size_t)n * K + k] = f2bf(tile[tx][ty + i]);
  }
}

// ---------------------------------------------------------------------------
// 128x128-tile GEMM (2-phase) for the two small GEMMs. Round-14: added the
// XOR bank swizzle (stage source pre-swizzled, read index XOR'd) — r1's
// linear layout was a 16-way conflict on every ds_read.
// ---------------------------------------------------------------------------
template<int EPI>
__global__ __launch_bounds__(256, 2)
void gemm_bt(const u16* __restrict__ A, const u16* __restrict__ BT,
             const float* __restrict__ bias, void* __restrict__ Cout,
             int K, int Nout) {
  __shared__ u16 lA[128 * 64];
  __shared__ u16 lB[128 * 64];
  const int tid  = threadIdx.x;
  const int wave = tid >> 6, lane = tid & 63;
  const int m0 = blockIdx.y * 128;
  const int n0 = blockIdx.x * 128;
  const int wm = (wave >> 1) * 64;
  const int wn = (wave & 1) * 64;

  frag_cd acc[4][4];
  #pragma unroll
  for (int i = 0; i < 4; ++i)
    #pragma unroll
    for (int j = 0; j < 4; ++j)
      acc[i][j] = (frag_cd)0.f;

  const int srow = lane >> 3;                      // 0..7 (== row&7)
  const int skc  = ((lane & 7) ^ srow) * 8;        // pre-swizzled k slot

  for (int k0 = 0; k0 < K; k0 += 64) {
    #pragma unroll
    for (int i = 0; i < 4; ++i) {
      int chunk = wave * 4 + i;
      int r = chunk * 8 + srow;
      const u16* ga = &A [(size_t)(m0 + r) * K + k0 + skc];
      const u16* gb = &BT[(size_t)(n0 + r) * K + k0 + skc];
      gload16(ga, &lA[chunk * 512 + lane * 8]);
      gload16(gb, &lB[chunk * 512 + lane * 8]);
    }
    __syncthreads();

    #pragma unroll
    for (int kk = 0; kk < 2; ++kk) {
      const int c15 = lane & 15;
      const int s   = kk * 4 + (lane >> 4);
      const int ko  = (s ^ (c15 & 7)) * 8;         // swizzled read slot
      frag_ab af[4], bfr[4];
      #pragma unroll
      for (int i = 0; i < 4; ++i) {
        af[i]  = *(const frag_ab*)&lA[(wm + i * 16 + c15) * 64 + ko];
        bfr[i] = *(const frag_ab*)&lB[(wn + i * 16 + c15) * 64 + ko];
      }
      #pragma unroll
      for (int i = 0; i < 4; ++i)
        #pragma unroll
        for (int j = 0; j < 4; ++j)
          acc[i][j] = __builtin_amdgcn_mfma_f32_16x16x32_bf16(
              af[i], bfr[j], acc[i][j], 0, 0, 0);
    }
    __syncthreads();
  }

  const int cr = (lane >> 4) * 4;
  const int cc = lane & 15;
  if (EPI == 0) {
    u16* H = (u16*)Cout;
    #pragma unroll
    for (int j = 0; j < 4; ++j) {
      int colg = n0 + wn + j * 16 + cc;
      float bv = bias[colg];
      #pragma unroll
      for (int i = 0; i < 4; ++i)
        #pragma unroll
        for (int t = 0; t < 4; ++t) {
          int rowg = m0 + wm + i * 16 + cr + t;
          float v = acc[i][j][t] + bv;
          v = v / (1.f + __expf(-v));
          H[(size_t)rowg * Nout + colg] = f2bf(v);
        }
    }
  } else {
    float* O = (float*)Cout;
    #pragma unroll
    for (int j = 0; j < 4; ++j) {
      int colg = n0 + wn + j * 16 + cc;
      if (colg < Nout) {
        float bv = bias[colg];
        #pragma unroll
        for (int i = 0; i < 4; ++i)
          #pragma unroll
          for (int t = 0; t < 4; ++t) {
            int rowg = m0 + wm + i * 16 + cr + t;
            O[(size_t)rowg * Nout + colg] = acc[i][j][t] + bv;
          }
      }
    }
  }
}

// ---------------------------------------------------------------------------
// Logits GEMM, round 14: m97 structure (128x128, BK=64, 4 waves, 32 KiB
// single-buffered LDS, plain C++ reads, compiler-scheduled waitcnts,
// ~3 blocks/CU) + the three verified fixes:
//   (a) XOR bank swizzle  (r1 had 1.5e8 conflicts = ~240us/CU)
//   (b) full-128B-line epilogue via LDS re-layout (r9: -245us vs scalar)
//   (c) bijective XCD swizzle, m-inner-32 (B-panel L2-resident per XCD)
// No manual vmcnt/lgkm/asm in the K-loop.
// ---------------------------------------------------------------------------
__global__ __launch_bounds__(256, 2)
void gemm3(const u16* __restrict__ A, const u16* __restrict__ BT,
           const float* __restrict__ bias, float* __restrict__ O) {
  __shared__ u16 lds[2 * 128 * 64];          // lA @0 (16 KB), lB @8192 elems
  u16* lA = lds;
  u16* lB = lds + 128 * 64;

  // (c) bijective XCD swizzle: 12608 = 8 x 1576; m-inner-32
  const int bid = blockIdx.x;
  const int wg  = (bid & 7) * (NWG3 / 8) + (bid >> 3);
  const int m0  = (wg & 31) * 128;
  const int n0  = (wg >> 5) * 128;           // up to 50304; rows < VPAD2: no clamp

  const int tid  = threadIdx.x;
  const int lane = tid & 63, wave = tid >> 6;
  const int wm = (wave >> 1) * 64;
  const int wn = (wave & 1) * 64;

  // (a) stage: thread t covers row i*32+(t>>3), slot t&7, source pre-swizzled
  const int trow = tid >> 3;                           // 0..31
  const int ke   = ((tid & 7) ^ (trow & 7)) * 8;       // swizzled k elems
  const u16* pa = A  + (size_t)(m0 + trow) * GK + ke;
  const u16* pb = BT + (size_t)(n0 + trow) * GK + ke;

  frag_cd acc[4][4];
  #pragma unroll
  for (int i = 0; i < 4; ++i)
    #pragma unroll
    for (int j = 0; j < 4; ++j)
      acc[i][j] = (frag_cd)0.f;

  const int c15 = lane & 15, q = lane >> 4;

  for (int kt = 0; kt < 16; ++kt) {
    const int k0 = kt * 64;
    #pragma unroll
    for (int i = 0; i < 4; ++i) {
      gload16(pa + (size_t)i * 32 * GK + k0, lA + i * 2048 + tid * 8);
      gload16(pb + (size_t)i * 32 * GK + k0, lB + i * 2048 + tid * 8);
    }
    __syncthreads();   // compiler drains vmcnt before barrier

    #pragma unroll
    for (int kk = 0; kk < 2; ++kk) {
      const int ko = ((kk * 4 + q) ^ (c15 & 7)) * 8;   // (a) swizzled read
      frag_ab af[4], bf[4];
      #pragma unroll
      for (int f = 0; f < 4; ++f) {
        af[f] = *(const frag_ab*)&lA[(wm + f * 16 + c15) * 64 + ko];
        bf[f] = *(const frag_ab*)&lB[(wn + f * 16 + c15) * 64 + ko];
      }
      #pragma unroll
      for (int i = 0; i < 4; ++i)
        #pragma unroll
        for (int j = 0; j < 4; ++j)
          acc[i][j] = __builtin_amdgcn_mfma_f32_16x16x32_bf16(
              af[i], bf[j], acc[i][j], 0, 0, 0);
    }
    __syncthreads();
  }

  // (b) epilogue: per-wave [16][68] f32 slice in (now-free) LDS; each
  // quarter-wave stores one row's 64 cols = 256 B contiguous f32x4.
  float* lfs = (float*)lds;
  const int lbase = wave * 1088;
  const int colg  = n0 + wn + c15 * 4;
  #pragma unroll
  for (int mf = 0; mf < 4; ++mf) {
    #pragma unroll
    for (int nf = 0; nf < 4; ++nf)
      #pragma unroll
      for (int t = 0; t < 4; ++t)
        lfs[lbase + (q * 4 + t) * 68 + nf * 16 + c15] = acc[mf][nf][t];
    #pragma unroll
    for (int p = 0; p < 4; ++p) {
      frag_cd v = *(const frag_cd*)&lfs[lbase + (p * 4 + q) * 68 + c15 * 4];
      const int rowg = m0 + wm + mf * 16 + p * 4 + q;
      if (colg + 3 < VOCAB) {
        frag_cd bv = *(const frag_cd*)&bias[colg];
        v += bv;
        *(frag_cd*)&O[(size_t)rowg * VOCAB + colg] = v;
      } else {
        #pragma unroll
        for (int t = 0; t < 4; ++t)
          if (colg + t < VOCAB)
            O[(size_t)rowg * VOCAB + colg + t] = v[t] + bias[colg + t];
      }
    }
  }
}

// ---------------------------------------------------------------------------
extern "C" void kernel_launch(void* const* d_in, const int* in_sizes, int n_in,
                              void* d_out, int out_size, void* d_ws, size_t ws_size,
                              hipStream_t stream) {
  const int*   tokens = (const int*)  d_in[0];
  const float* E      = (const float*)d_in[1];
  const float* W1     = (const float*)d_in[2];
  const float* b1     = (const float*)d_in[3];
  const float* W2     = (const float*)d_in[4];
  const float* b2     = (const float*)d_in[5];
  const float* Wout   = (const float*)d_in[6];
  const float* bout   = (const float*)d_in[7];
  float* out = (float*)d_out;

  // Workspace layout (~153.7 MB)
  char* p = (char*)d_ws;
  u16* XB  = (u16*)p; p += (size_t)MROWS * XDIM  * 2;   // 25.2 MB
  u16* WOT = (u16*)p; p += (size_t)VPAD2 * EMBED * 2;   // 103.3 MB
  u16* H1  = (u16*)p; p += (size_t)MROWS * EMBED * 2;   //  8.4 MB
  u16* H2  = (u16*)p; p += (size_t)MROWS * EMBED * 2;   //  8.4 MB
  u16* W1T = (u16*)p; p += (size_t)EMBED * XDIM  * 2;   //  6.3 MB
  u16* W2T = (u16*)p; p += (size_t)EMBED * EMBED * 2;   //  2.1 MB

  gather_x<<<MROWS, 256, 0, stream>>>(tokens, E, XB);
  transpose_cvt<<<dim3(EMBED/32, XDIM/32),  256, 0, stream>>>(W1,   W1T, XDIM,  EMBED);
  transpose_cvt<<<dim3(EMBED/32, EMBED/32), 256, 0, stream>>>(W2,   W2T, EMBED, EMBED);
  transpose_cvt<<<dim3(VPAD2/32, EMBED/32), 256, 0, stream>>>(Wout, WOT, EMBED, VOCAB);

  gemm_bt<0><<<dim3(EMBED/128, MROWS/128), 256, 0, stream>>>(XB, W1T, b1, H1, XDIM,  EMBED);
  gemm_bt<0><<<dim3(EMBED/128, MROWS/128), 256, 0, stream>>>(H1, W2T, b2, H2, EMBED, EMBED);

  gemm3<<<NWG3, 256, 0, stream>>>(H2, WOT, bout, out);
}

// Round 15
// 808.616 us; speedup vs baseline: 1.0437x; 1.0437x over previous
//
#include <hip/hip_runtime.h>
#include <hip/hip_bf16.h>

// Problem constants (fixed by reference)
#define SEQ    2048
#define BATCH  2
#define MROWS  (SEQ*BATCH)    // 4096
#define EMBED  1024
#define KCTX   3
#define XDIM   (KCTX*EMBED)   // 3072
#define VOCAB  50257
#define VPAD2  50432          // Wout^T rows allocated (zero tail: no row clamps)
#define GK     1024           // K of the logits GEMM
#define NBLKN  197            // ceil(VOCAB/256)
#define NWG    (16*NBLKN)     // 3152 blocks, divisible by 8

using u16 = unsigned short;
typedef __attribute__((ext_vector_type(8))) short   frag_ab;  // 8 bf16
typedef __attribute__((ext_vector_type(4))) float   frag_cd;  // 4 f32

__device__ __forceinline__ u16 f2bf(float f) {
  union { float f; unsigned u; } v; v.f = f;
  unsigned r = v.u + 0x7fffu + ((v.u >> 16) & 1u);
  return (u16)(r >> 16);
}

__device__ __forceinline__ void gload16(const u16* g, const u16* l) {
  __builtin_amdgcn_global_load_lds((const __attribute__((address_space(1))) void*)g,
                                   (__attribute__((address_space(3))) void*)l, 16, 0, 0);
}

// ---------------------------------------------------------------------------
// Gather: XB[r][i*1024+c] = bf16(E[tok(r,i)][c]); r = s*BATCH+b
// ---------------------------------------------------------------------------
__global__ void gather_x(const int* __restrict__ tokens,
                         const float* __restrict__ E,
                         u16* __restrict__ XB) {
  const int r = blockIdx.x;
  const int s = r >> 1, b = r & 1;
  #pragma unroll
  for (int i = 0; i < KCTX; ++i) {
    int t = s + i - (KCTX - 1);
    int tok = (t >= 0) ? tokens[t * BATCH + b] : 0;
    const float* src = &E[(size_t)tok * EMBED];
    u16* dst = &XB[(size_t)r * XDIM + i * EMBED];
    int c = threadIdx.x * 4;
    float4 v = *(const float4*)&src[c];
    u16 o[4] = { f2bf(v.x), f2bf(v.y), f2bf(v.z), f2bf(v.w) };
    *(ulong1*)&dst[c] = *(ulong1*)o;
  }
}

// ---------------------------------------------------------------------------
// Transpose + f32->bf16: W (K x N) -> WT (Npad x K). n >= N writes 0.
// ---------------------------------------------------------------------------
__global__ void transpose_cvt(const float* __restrict__ W,
                              u16* __restrict__ WT,
                              int K, int N) {
  __shared__ float tile[32][33];
  const int nb = blockIdx.x * 32, kb = blockIdx.y * 32;
  const int tx = threadIdx.x & 31, ty = threadIdx.x >> 5;
  #pragma unroll
  for (int i = 0; i < 32; i += 8) {
    int k = kb + ty + i, n = nb + tx;
    tile[ty + i][tx] = (n < N) ? W[(size_t)k * N + n] : 0.f;
  }
  __syncthreads();
  #pragma unroll
  for (int i = 0; i < 32; i += 8) {
    int n = nb + ty + i, k = kb + tx;
    WT[(size_t)n * K + k] = f2bf(tile[tx][ty + i]);
  }
}

// ---------------------------------------------------------------------------
// 128x128-tile GEMM for the two small GEMMs (r14 version: XOR bank swizzle).
// ---------------------------------------------------------------------------
template<int EPI>
__global__ __launch_bounds__(256, 2)
void gemm_bt(const u16* __restrict__ A, const u16* __restrict__ BT,
             const float* __restrict__ bias, void* __restrict__ Cout,
             int K, int Nout) {
  __shared__ u16 lA[128 * 64];
  __shared__ u16 lB[128 * 64];
  const int tid  = threadIdx.x;
  const int wave = tid >> 6, lane = tid & 63;
  const int m0 = blockIdx.y * 128;
  const int n0 = blockIdx.x * 128;
  const int wm = (wave >> 1) * 64;
  const int wn = (wave & 1) * 64;

  frag_cd acc[4][4];
  #pragma unroll
  for (int i = 0; i < 4; ++i)
    #pragma unroll
    for (int j = 0; j < 4; ++j)
      acc[i][j] = (frag_cd)0.f;

  const int srow = lane >> 3;                      // 0..7 (== row&7)
  const int skc  = ((lane & 7) ^ srow) * 8;        // pre-swizzled k slot

  for (int k0 = 0; k0 < K; k0 += 64) {
    #pragma unroll
    for (int i = 0; i < 4; ++i) {
      int chunk = wave * 4 + i;
      int r = chunk * 8 + srow;
      const u16* ga = &A [(size_t)(m0 + r) * K + k0 + skc];
      const u16* gb = &BT[(size_t)(n0 + r) * K + k0 + skc];
      gload16(ga, &lA[chunk * 512 + lane * 8]);
      gload16(gb, &lB[chunk * 512 + lane * 8]);
    }
    __syncthreads();

    #pragma unroll
    for (int kk = 0; kk < 2; ++kk) {
      const int c15 = lane & 15;
      const int s   = kk * 4 + (lane >> 4);
      const int ko  = (s ^ (c15 & 7)) * 8;         // swizzled read slot
      frag_ab af[4], bfr[4];
      #pragma unroll
      for (int i = 0; i < 4; ++i) {
        af[i]  = *(const frag_ab*)&lA[(wm + i * 16 + c15) * 64 + ko];
        bfr[i] = *(const frag_ab*)&lB[(wn + i * 16 + c15) * 64 + ko];
      }
      #pragma unroll
      for (int i = 0; i < 4; ++i)
        #pragma unroll
        for (int j = 0; j < 4; ++j)
          acc[i][j] = __builtin_amdgcn_mfma_f32_16x16x32_bf16(
              af[i], bfr[j], acc[i][j], 0, 0, 0);
    }
    __syncthreads();
  }

  const int cr = (lane >> 4) * 4;
  const int cc = lane & 15;
  if (EPI == 0) {
    u16* H = (u16*)Cout;
    #pragma unroll
    for (int j = 0; j < 4; ++j) {
      int colg = n0 + wn + j * 16 + cc;
      float bv = bias[colg];
      #pragma unroll
      for (int i = 0; i < 4; ++i)
        #pragma unroll
        for (int t = 0; t < 4; ++t) {
          int rowg = m0 + wm + i * 16 + cr + t;
          float v = acc[i][j][t] + bv;
          v = v / (1.f + __expf(-v));
          H[(size_t)rowg * Nout + colg] = f2bf(v);
        }
    }
  } else {
    float* O = (float*)Cout;
    #pragma unroll
    for (int j = 0; j < 4; ++j) {
      int colg = n0 + wn + j * 16 + cc;
      if (colg < Nout) {
        float bv = bias[colg];
        #pragma unroll
        for (int i = 0; i < 4; ++i)
          #pragma unroll
          for (int t = 0; t < 4; ++t) {
            int rowg = m0 + wm + i * 16 + cr + t;
            O[(size_t)rowg * Nout + colg] = acc[i][j][t] + bv;
          }
      }
    }
  }
}

// ---------------------------------------------------------------------------
// Logits GEMM, round 15 = round 9 champion (256x256, BK=32, 3 LDS parities,
// depth-2 prefetch, vmcnt(4), one barrier/tile, full-line LDS epilogue)
// with ONE change: NONTEMPORAL output stores, so the 823 MB write stream
// stops evicting the 103 MB B-panel from L3 (FETCH was 5.5x B's size).
// ---------------------------------------------------------------------------
#define BARR   asm volatile("s_barrier" ::: "memory")
#define VMCNT4 asm volatile("s_waitcnt vmcnt(4)" ::: "memory")
#define LGKM0  asm volatile("s_waitcnt lgkmcnt(0)" ::: "memory")
#define SCHED0 __builtin_amdgcn_sched_barrier(0)
#define PRIO1  __builtin_amdgcn_s_setprio(1)
#define PRIO0  __builtin_amdgcn_s_setprio(0)

#define DSREAD(DST, AREG, IMM) \
  asm volatile("ds_read_b128 %0, %1 offset:%2" : "=v"(DST) : "v"(AREG), "i"(IMM))

#define ADV { pa0 += 32; pa1 += 32; pb0 += 32; pb1 += 32; }

#define KT(REGH, REGW, HIMM, WIMM, WP) { \
  VMCNT4; BARR; \
  gload16(pa0, (const u16*)(smraw + (WP)         + stoff)); \
  gload16(pa1, (const u16*)(smraw + (WP) +  8192 + stoff)); \
  gload16(pb0, (const u16*)(smraw + (WP) + 16384 + stoff)); \
  gload16(pb1, (const u16*)(smraw + (WP) + 24576 + stoff)); \
  ADV; \
  DSREAD(wF[0], REGW, (WIMM) + 0*1024); \
  DSREAD(wF[1], REGW, (WIMM) + 1*1024); \
  DSREAD(wF[2], REGW, (WIMM) + 2*1024); \
  DSREAD(wF[3], REGW, (WIMM) + 3*1024); \
  DSREAD(hF[0], REGH, (HIMM) + 0*1024); \
  DSREAD(hF[1], REGH, (HIMM) + 1*1024); \
  DSREAD(hF[2], REGH, (HIMM) + 2*1024); \
  DSREAD(hF[3], REGH, (HIMM) + 3*1024); \
  DSREAD(hF[4], REGH, (HIMM) + 4*1024); \
  DSREAD(hF[5], REGH, (HIMM) + 5*1024); \
  DSREAD(hF[6], REGH, (HIMM) + 6*1024); \
  DSREAD(hF[7], REGH, (HIMM) + 7*1024); \
  LGKM0; SCHED0; \
  PRIO1; \
  _Pragma("unroll") for (int nf = 0; nf < 4; ++nf) \
  _Pragma("unroll") for (int mf = 0; mf < 8; ++mf) \
    acc[mf][nf] = __builtin_amdgcn_mfma_f32_16x16x32_bf16(hF[mf], wF[nf], acc[mf][nf], 0, 0, 0); \
  PRIO0; SCHED0; }

__global__ __launch_bounds__(512, 2)
void gemm256(const u16* __restrict__ A, const u16* __restrict__ BT,
             const float* __restrict__ bias, float* __restrict__ O) {
  extern __shared__ char smraw[];

  // Bijective chunked XCD swizzle; M-innermost so one XCD reuses one B-panel.
  const int bid = blockIdx.x;
  const int wg  = (bid & 7) * (NWG / 8) + (bid >> 3);
  const int m0  = (wg & 15) * 256;
  const int n0  = (wg >> 4) * 256;

  const int tid  = threadIdx.x;
  const int lane = tid & 63, wave = tid >> 6;
  const int wm = wave >> 2, wn = wave & 3;   // 2 x 4 waves

  // ---- staging constants (gload_lds dest = base + lane*16: linear) ----
  const int stoff = wave * 1024 + lane * 16;               // LDS byte offset
  const int srow  = wave * 16 + (lane >> 2);               // tile row (+128 for *1)
  const int ke    = ((lane & 3) ^ ((lane >> 3) & 3)) * 8;  // pre-swz k elems

  const u16* pa0 = A + (size_t)(m0 + srow      ) * GK + ke;
  const u16* pa1 = A + (size_t)(m0 + srow + 128) * GK + ke;
  const u16* pb0 = BT + (size_t)(n0 + srow      ) * GK + ke;   // VPAD2: no clamp
  const u16* pb1 = BT + (size_t)(n0 + srow + 128) * GK + ke;

  // ---- ds_read base regs (swizzle: 16B-slot ^= (row>>1)&3) ----
  const unsigned dynbase = (unsigned)(size_t)(__attribute__((address_space(3))) char*)smraw;
  const int c = lane & 15, q = lane >> 4;
  const unsigned swq  = ((unsigned)q << 4) ^ (((unsigned)(c >> 1) & 3u) << 4);
  const unsigned regH_lo = dynbase + (unsigned)((wm * 128 + c) * 64) + swq;            // H2 rows (m)
  const unsigned regW_lo = dynbase + 16384u + (unsigned)((wn * 64 + c) * 64) + swq;    // WOT rows (vocab)
  const unsigned regH_hi = regH_lo + 65536u;   // parity 2
  const unsigned regW_hi = regW_lo + 65536u;

  frag_ab hF[8], wF[4];
  frag_cd acc[8][4];
  #pragma unroll
  for (int i = 0; i < 8; ++i)
    #pragma unroll
    for (int j = 0; j < 4; ++j)
      acc[i][j] = (frag_cd)0.f;

  // ---- prologue: stage tiles 0 -> par0, 1 -> par1 ----
  gload16(pa0, (const u16*)(smraw +     0 + stoff));
  gload16(pa1, (const u16*)(smraw +  8192 + stoff));
  gload16(pb0, (const u16*)(smraw + 16384 + stoff));
  gload16(pb1, (const u16*)(smraw + 24576 + stoff));
  ADV;
  gload16(pa0, (const u16*)(smraw + 32768 +     0 + stoff));
  gload16(pa1, (const u16*)(smraw + 32768 +  8192 + stoff));
  gload16(pb0, (const u16*)(smraw + 32768 + 16384 + stoff));
  gload16(pb1, (const u16*)(smraw + 32768 + 24576 + stoff));
  ADV;

  // ---- main loop: 32 K-tiles = 10 x (par0,par1,par2) + par0,par1 ----
  #pragma unroll 1
  for (int tt = 0; tt < 10; ++tt) {
    KT(regH_lo, regW_lo,     0,     0, 65536);   // read par0, stage -> par2
    KT(regH_lo, regW_lo, 32768, 32768,     0);   // read par1, stage -> par0
    KT(regH_hi, regW_hi,     0,     0, 32768);   // read par2, stage -> par1
  }
  KT(regH_lo, regW_lo,     0,     0, 65536);     // t=30
  KT(regH_lo, regW_lo, 32768, 32768,     0);     // t=31 (garbage stages, in-ws)

  // drain garbage stages + all LDS ops, then barrier before LDS reuse
  asm volatile("s_waitcnt vmcnt(0) lgkmcnt(0)" ::: "memory");
  BARR;

  // ---- epilogue: LDS re-layout -> full-128B-line NONTEMPORAL stores ----
  float* lfs = (float*)smraw;
  const int colg = n0 + wn * 64 + c * 4;
  #pragma unroll
  for (int mf = 0; mf < 8; ++mf) {
    const int lbase = wave * 1088 + (mf & 1) * 8704;
    #pragma unroll
    for (int nf = 0; nf < 4; ++nf)
      #pragma unroll
      for (int t = 0; t < 4; ++t)
        lfs[lbase + (q * 4 + t) * 68 + nf * 16 + c] = acc[mf][nf][t];
    #pragma unroll
    for (int p = 0; p < 4; ++p) {
      frag_cd v = *(const frag_cd*)&lfs[lbase + (p * 4 + q) * 68 + c * 4];
      const int rowg = m0 + wm * 128 + mf * 16 + p * 4 + q;
      if (colg + 3 < VOCAB) {
        frag_cd bv = *(const frag_cd*)&bias[colg];
        v += bv;
        __builtin_nontemporal_store(v, (frag_cd*)&O[(size_t)rowg * VOCAB + colg]);
      } else {
        #pragma unroll
        for (int t = 0; t < 4; ++t)
          if (colg + t < VOCAB)
            O[(size_t)rowg * VOCAB + colg + t] = v[t] + bias[colg + t];
      }
    }
  }
}

// ---------------------------------------------------------------------------
extern "C" void kernel_launch(void* const* d_in, const int* in_sizes, int n_in,
                              void* d_out, int out_size, void* d_ws, size_t ws_size,
                              hipStream_t stream) {
  const int*   tokens = (const int*)  d_in[0];
  const float* E      = (const float*)d_in[1];
  const float* W1     = (const float*)d_in[2];
  const float* b1     = (const float*)d_in[3];
  const float* W2     = (const float*)d_in[4];
  const float* b2     = (const float*)d_in[5];
  const float* Wout   = (const float*)d_in[6];
  const float* bout   = (const float*)d_in[7];
  float* out = (float*)d_out;

  // Workspace layout (~153.7 MB); K-loop over-advance reads land inside ws
  // (WOT -> H1, H2 -> W1T).
  char* p = (char*)d_ws;
  u16* XB  = (u16*)p; p += (size_t)MROWS * XDIM  * 2;   // 25.2 MB
  u16* WOT = (u16*)p; p += (size_t)VPAD2 * EMBED * 2;   // 103.3 MB
  u16* H1  = (u16*)p; p += (size_t)MROWS * EMBED * 2;   //  8.4 MB
  u16* H2  = (u16*)p; p += (size_t)MROWS * EMBED * 2;   //  8.4 MB
  u16* W1T = (u16*)p; p += (size_t)EMBED * XDIM  * 2;   //  6.3 MB
  u16* W2T = (u16*)p; p += (size_t)EMBED * EMBED * 2;   //  2.1 MB

  hipFuncSetAttribute((const void*)gemm256,
                      hipFuncAttributeMaxDynamicSharedMemorySize, 98304);

  gather_x<<<MROWS, 256, 0, stream>>>(tokens, E, XB);
  transpose_cvt<<<dim3(EMBED/32, XDIM/32),  256, 0, stream>>>(W1,   W1T, XDIM,  EMBED);
  transpose_cvt<<<dim3(EMBED/32, EMBED/32), 256, 0, stream>>>(W2,   W2T, EMBED, EMBED);
  transpose_cvt<<<dim3(VPAD2/32, EMBED/32), 256, 0, stream>>>(Wout, WOT, EMBED, VOCAB);

  gemm_bt<0><<<dim3(EMBED/128, MROWS/128), 256, 0, stream>>>(XB, W1T, b1, H1, XDIM,  EMBED);
  gemm_bt<0><<<dim3(EMBED/128, MROWS/128), 256, 0, stream>>>(H1, W2T, b2, H2, EMBED, EMBED);

  gemm256<<<NWG, 512, 98304, stream>>>(H2, WOT, bout, out);
}

// Round 17
// 796.505 us; speedup vs baseline: 1.0595x; 1.0152x over previous
//
#include <hip/hip_runtime.h>
#include <hip/hip_bf16.h>

// Problem constants (fixed by reference)
#define SEQ    2048
#define BATCH  2
#define MROWS  (SEQ*BATCH)    // 4096
#define EMBED  1024
#define KCTX   3
#define XDIM   (KCTX*EMBED)   // 3072
#define VOCAB  50257
#define VPAD2  50432          // Wout^T rows allocated (zero tail: no row clamps)
#define GK     1024           // K of the logits GEMM
#define NBLKN  197            // ceil(VOCAB/256)
#define NWG    (16*NBLKN)     // 3152 blocks, divisible by 8

using u16 = unsigned short;
typedef __attribute__((ext_vector_type(8))) short   frag_ab;  // 8 bf16
typedef __attribute__((ext_vector_type(4))) float   frag_cd;  // 4 f32

__device__ __forceinline__ u16 f2bf(float f) {
  union { float f; unsigned u; } v; v.f = f;
  unsigned r = v.u + 0x7fffu + ((v.u >> 16) & 1u);
  return (u16)(r >> 16);
}

__device__ __forceinline__ void gload16(const u16* g, const u16* l) {
  __builtin_amdgcn_global_load_lds((const __attribute__((address_space(1))) void*)g,
                                   (__attribute__((address_space(3))) void*)l, 16, 0, 0);
}

// ---------------------------------------------------------------------------
// Gather: XB[r][i*1024+c] = bf16(E[tok(r,i)][c]); r = s*BATCH+b
// ---------------------------------------------------------------------------
__global__ void gather_x(const int* __restrict__ tokens,
                         const float* __restrict__ E,
                         u16* __restrict__ XB) {
  const int r = blockIdx.x;
  const int s = r >> 1, b = r & 1;
  #pragma unroll
  for (int i = 0; i < KCTX; ++i) {
    int t = s + i - (KCTX - 1);
    int tok = (t >= 0) ? tokens[t * BATCH + b] : 0;
    const float* src = &E[(size_t)tok * EMBED];
    u16* dst = &XB[(size_t)r * XDIM + i * EMBED];
    int c = threadIdx.x * 4;
    float4 v = *(const float4*)&src[c];
    u16 o[4] = { f2bf(v.x), f2bf(v.y), f2bf(v.z), f2bf(v.w) };
    *(ulong1*)&dst[c] = *(ulong1*)o;
  }
}

// ---------------------------------------------------------------------------
// Transpose + f32->bf16: W (K x N) -> WT (Npad x K). n >= N writes 0.
// ---------------------------------------------------------------------------
__global__ void transpose_cvt(const float* __restrict__ W,
                              u16* __restrict__ WT,
                              int K, int N) {
  __shared__ float tile[32][33];
  const int nb = blockIdx.x * 32, kb = blockIdx.y * 32;
  const int tx = threadIdx.x & 31, ty = threadIdx.x >> 5;
  #pragma unroll
  for (int i = 0; i < 32; i += 8) {
    int k = kb + ty + i, n = nb + tx;
    tile[ty + i][tx] = (n < N) ? W[(size_t)k * N + n] : 0.f;
  }
  __syncthreads();
  #pragma unroll
  for (int i = 0; i < 32; i += 8) {
    int n = nb + ty + i, k = kb + tx;
    WT[(size_t)n * K + k] = f2bf(tile[tx][ty + i]);
  }
}

// ---------------------------------------------------------------------------
// 128x128-tile GEMM for the two small GEMMs (r14 version: XOR bank swizzle).
// ---------------------------------------------------------------------------
template<int EPI>
__global__ __launch_bounds__(256, 2)
void gemm_bt(const u16* __restrict__ A, const u16* __restrict__ BT,
             const float* __restrict__ bias, void* __restrict__ Cout,
             int K, int Nout) {
  __shared__ u16 lA[128 * 64];
  __shared__ u16 lB[128 * 64];
  const int tid  = threadIdx.x;
  const int wave = tid >> 6, lane = tid & 63;
  const int m0 = blockIdx.y * 128;
  const int n0 = blockIdx.x * 128;
  const int wm = (wave >> 1) * 64;
  const int wn = (wave & 1) * 64;

  frag_cd acc[4][4];
  #pragma unroll
  for (int i = 0; i < 4; ++i)
    #pragma unroll
    for (int j = 0; j < 4; ++j)
      acc[i][j] = (frag_cd)0.f;

  const int srow = lane >> 3;                      // 0..7 (== row&7)
  const int skc  = ((lane & 7) ^ srow) * 8;        // pre-swizzled k slot

  for (int k0 = 0; k0 < K; k0 += 64) {
    #pragma unroll
    for (int i = 0; i < 4; ++i) {
      int chunk = wave * 4 + i;
      int r = chunk * 8 + srow;
      const u16* ga = &A [(size_t)(m0 + r) * K + k0 + skc];
      const u16* gb = &BT[(size_t)(n0 + r) * K + k0 + skc];
      gload16(ga, &lA[chunk * 512 + lane * 8]);
      gload16(gb, &lB[chunk * 512 + lane * 8]);
    }
    __syncthreads();

    #pragma unroll
    for (int kk = 0; kk < 2; ++kk) {
      const int c15 = lane & 15;
      const int s   = kk * 4 + (lane >> 4);
      const int ko  = (s ^ (c15 & 7)) * 8;         // swizzled read slot
      frag_ab af[4], bfr[4];
      #pragma unroll
      for (int i = 0; i < 4; ++i) {
        af[i]  = *(const frag_ab*)&lA[(wm + i * 16 + c15) * 64 + ko];
        bfr[i] = *(const frag_ab*)&lB[(wn + i * 16 + c15) * 64 + ko];
      }
      #pragma unroll
      for (int i = 0; i < 4; ++i)
        #pragma unroll
        for (int j = 0; j < 4; ++j)
          acc[i][j] = __builtin_amdgcn_mfma_f32_16x16x32_bf16(
              af[i], bfr[j], acc[i][j], 0, 0, 0);
    }
    __syncthreads();
  }

  const int cr = (lane >> 4) * 4;
  const int cc = lane & 15;
  if (EPI == 0) {
    u16* H = (u16*)Cout;
    #pragma unroll
    for (int j = 0; j < 4; ++j) {
      int colg = n0 + wn + j * 16 + cc;
      float bv = bias[colg];
      #pragma unroll
      for (int i = 0; i < 4; ++i)
        #pragma unroll
        for (int t = 0; t < 4; ++t) {
          int rowg = m0 + wm + i * 16 + cr + t;
          float v = acc[i][j][t] + bv;
          v = v / (1.f + __expf(-v));
          H[(size_t)rowg * Nout + colg] = f2bf(v);
        }
    }
  } else {
    float* O = (float*)Cout;
    #pragma unroll
    for (int j = 0; j < 4; ++j) {
      int colg = n0 + wn + j * 16 + cc;
      if (colg < Nout) {
        float bv = bias[colg];
        #pragma unroll
        for (int i = 0; i < 4; ++i)
          #pragma unroll
          for (int t = 0; t < 4; ++t) {
            int rowg = m0 + wm + i * 16 + cr + t;
            O[(size_t)rowg * Nout + colg] = acc[i][j][t] + bv;
          }
      }
    }
  }
}

// ---------------------------------------------------------------------------
// Logits GEMM = round-9 champion (256x256, BK=32, 3 LDS parities, depth-2
// prefetch, counted vmcnt(4), one barrier/tile, full-line LDS epilogue with
// PLAIN stores — r15's nontemporal variant measured +64us / +130MB WRITE
// and is reverted).
// ---------------------------------------------------------------------------
#define BARR   asm volatile("s_barrier" ::: "memory")
#define VMCNT4 asm volatile("s_waitcnt vmcnt(4)" ::: "memory")
#define LGKM0  asm volatile("s_waitcnt lgkmcnt(0)" ::: "memory")
#define SCHED0 __builtin_amdgcn_sched_barrier(0)
#define PRIO1  __builtin_amdgcn_s_setprio(1)
#define PRIO0  __builtin_amdgcn_s_setprio(0)

#define DSREAD(DST, AREG, IMM) \
  asm volatile("ds_read_b128 %0, %1 offset:%2" : "=v"(DST) : "v"(AREG), "i"(IMM))

#define ADV { pa0 += 32; pa1 += 32; pb0 += 32; pb1 += 32; }

#define KT(REGH, REGW, HIMM, WIMM, WP) { \
  VMCNT4; BARR; \
  gload16(pa0, (const u16*)(smraw + (WP)         + stoff)); \
  gload16(pa1, (const u16*)(smraw + (WP) +  8192 + stoff)); \
  gload16(pb0, (const u16*)(smraw + (WP) + 16384 + stoff)); \
  gload16(pb1, (const u16*)(smraw + (WP) + 24576 + stoff)); \
  ADV; \
  DSREAD(wF[0], REGW, (WIMM) + 0*1024); \
  DSREAD(wF[1], REGW, (WIMM) + 1*1024); \
  DSREAD(wF[2], REGW, (WIMM) + 2*1024); \
  DSREAD(wF[3], REGW, (WIMM) + 3*1024); \
  DSREAD(hF[0], REGH, (HIMM) + 0*1024); \
  DSREAD(hF[1], REGH, (HIMM) + 1*1024); \
  DSREAD(hF[2], REGH, (HIMM) + 2*1024); \
  DSREAD(hF[3], REGH, (HIMM) + 3*1024); \
  DSREAD(hF[4], REGH, (HIMM) + 4*1024); \
  DSREAD(hF[5], REGH, (HIMM) + 5*1024); \
  DSREAD(hF[6], REGH, (HIMM) + 6*1024); \
  DSREAD(hF[7], REGH, (HIMM) + 7*1024); \
  LGKM0; SCHED0; \
  PRIO1; \
  _Pragma("unroll") for (int nf = 0; nf < 4; ++nf) \
  _Pragma("unroll") for (int mf = 0; mf < 8; ++mf) \
    acc[mf][nf] = __builtin_amdgcn_mfma_f32_16x16x32_bf16(hF[mf], wF[nf], acc[mf][nf], 0, 0, 0); \
  PRIO0; SCHED0; }

__global__ __launch_bounds__(512, 2)
void gemm256(const u16* __restrict__ A, const u16* __restrict__ BT,
             const float* __restrict__ bias, float* __restrict__ O) {
  extern __shared__ char smraw[];

  // Bijective chunked XCD swizzle; M-innermost so one XCD reuses one B-panel.
  const int bid = blockIdx.x;
  const int wg  = (bid & 7) * (NWG / 8) + (bid >> 3);
  const int m0  = (wg & 15) * 256;
  const int n0  = (wg >> 4) * 256;

  const int tid  = threadIdx.x;
  const int lane = tid & 63, wave = tid >> 6;
  const int wm = wave >> 2, wn = wave & 3;   // 2 x 4 waves

  // ---- staging constants (gload_lds dest = base + lane*16: linear) ----
  const int stoff = wave * 1024 + lane * 16;               // LDS byte offset
  const int srow  = wave * 16 + (lane >> 2);               // tile row (+128 for *1)
  const int ke    = ((lane & 3) ^ ((lane >> 3) & 3)) * 8;  // pre-swz k elems

  const u16* pa0 = A + (size_t)(m0 + srow      ) * GK + ke;
  const u16* pa1 = A + (size_t)(m0 + srow + 128) * GK + ke;
  const u16* pb0 = BT + (size_t)(n0 + srow      ) * GK + ke;   // VPAD2: no clamp
  const u16* pb1 = BT + (size_t)(n0 + srow + 128) * GK + ke;

  // ---- ds_read base regs (swizzle: 16B-slot ^= (row>>1)&3) ----
  const unsigned dynbase = (unsigned)(size_t)(__attribute__((address_space(3))) char*)smraw;
  const int c = lane & 15, q = lane >> 4;
  const unsigned swq  = ((unsigned)q << 4) ^ (((unsigned)(c >> 1) & 3u) << 4);
  const unsigned regH_lo = dynbase + (unsigned)((wm * 128 + c) * 64) + swq;            // H2 rows (m)
  const unsigned regW_lo = dynbase + 16384u + (unsigned)((wn * 64 + c) * 64) + swq;    // WOT rows (vocab)
  const unsigned regH_hi = regH_lo + 65536u;   // parity 2
  const unsigned regW_hi = regW_lo + 65536u;

  frag_ab hF[8], wF[4];
  frag_cd acc[8][4];
  #pragma unroll
  for (int i = 0; i < 8; ++i)
    #pragma unroll
    for (int j = 0; j < 4; ++j)
      acc[i][j] = (frag_cd)0.f;

  // ---- prologue: stage tiles 0 -> par0, 1 -> par1 ----
  gload16(pa0, (const u16*)(smraw +     0 + stoff));
  gload16(pa1, (const u16*)(smraw +  8192 + stoff));
  gload16(pb0, (const u16*)(smraw + 16384 + stoff));
  gload16(pb1, (const u16*)(smraw + 24576 + stoff));
  ADV;
  gload16(pa0, (const u16*)(smraw + 32768 +     0 + stoff));
  gload16(pa1, (const u16*)(smraw + 32768 +  8192 + stoff));
  gload16(pb0, (const u16*)(smraw + 32768 + 16384 + stoff));
  gload16(pb1, (const u16*)(smraw + 32768 + 24576 + stoff));
  ADV;

  // ---- main loop: 32 K-tiles = 10 x (par0,par1,par2) + par0,par1 ----
  #pragma unroll 1
  for (int tt = 0; tt < 10; ++tt) {
    KT(regH_lo, regW_lo,     0,     0, 65536);   // read par0, stage -> par2
    KT(regH_lo, regW_lo, 32768, 32768,     0);   // read par1, stage -> par0
    KT(regH_hi, regW_hi,     0,     0, 32768);   // read par2, stage -> par1
  }
  KT(regH_lo, regW_lo,     0,     0, 65536);     // t=30
  KT(regH_lo, regW_lo, 32768, 32768,     0);     // t=31 (garbage stages, in-ws)

  // drain garbage stages + all LDS ops, then barrier before LDS reuse
  asm volatile("s_waitcnt vmcnt(0) lgkmcnt(0)" ::: "memory");
  BARR;

  // ---- epilogue: LDS re-layout -> full-128B-line stores ----
  float* lfs = (float*)smraw;
  const int colg = n0 + wn * 64 + c * 4;
  #pragma unroll
  for (int mf = 0; mf < 8; ++mf) {
    const int lbase = wave * 1088 + (mf & 1) * 8704;
    #pragma unroll
    for (int nf = 0; nf < 4; ++nf)
      #pragma unroll
      for (int t = 0; t < 4; ++t)
        lfs[lbase + (q * 4 + t) * 68 + nf * 16 + c] = acc[mf][nf][t];
    #pragma unroll
    for (int p = 0; p < 4; ++p) {
      frag_cd v = *(const frag_cd*)&lfs[lbase + (p * 4 + q) * 68 + c * 4];
      const int rowg = m0 + wm * 128 + mf * 16 + p * 4 + q;
      if (colg + 3 < VOCAB) {
        frag_cd bv = *(const frag_cd*)&bias[colg];
        v += bv;
        *(frag_cd*)&O[(size_t)rowg * VOCAB + colg] = v;
      } else {
        #pragma unroll
        for (int t = 0; t < 4; ++t)
          if (colg + t < VOCAB)
            O[(size_t)rowg * VOCAB + colg + t] = v[t] + bias[colg + t];
      }
    }
  }
}

// ---------------------------------------------------------------------------
extern "C" void kernel_launch(void* const* d_in, const int* in_sizes, int n_in,
                              void* d_out, int out_size, void* d_ws, size_t ws_size,
                              hipStream_t stream) {
  const int*   tokens = (const int*)  d_in[0];
  const float* E      = (const float*)d_in[1];
  const float* W1     = (const float*)d_in[2];
  const float* b1     = (const float*)d_in[3];
  const float* W2     = (const float*)d_in[4];
  const float* b2     = (const float*)d_in[5];
  const float* Wout   = (const float*)d_in[6];
  const float* bout   = (const float*)d_in[7];
  float* out = (float*)d_out;

  // Workspace layout (~153.7 MB); K-loop over-advance reads land inside ws
  // (WOT -> H1, H2 -> W1T).
  char* p = (char*)d_ws;
  u16* XB  = (u16*)p; p += (size_t)MROWS * XDIM  * 2;   // 25.2 MB
  u16* WOT = (u16*)p; p += (size_t)VPAD2 * EMBED * 2;   // 103.3 MB
  u16* H1  = (u16*)p; p += (size_t)MROWS * EMBED * 2;   //  8.4 MB
  u16* H2  = (u16*)p; p += (size_t)MROWS * EMBED * 2;   //  8.4 MB
  u16* W1T = (u16*)p; p += (size_t)EMBED * XDIM  * 2;   //  6.3 MB
  u16* W2T = (u16*)p; p += (size_t)EMBED * EMBED * 2;   //  2.1 MB

  hipFuncSetAttribute((const void*)gemm256,
                      hipFuncAttributeMaxDynamicSharedMemorySize, 98304);

  gather_x<<<MROWS, 256, 0, stream>>>(tokens, E, XB);
  transpose_cvt<<<dim3(EMBED/32, XDIM/32),  256, 0, stream>>>(W1,   W1T, XDIM,  EMBED);
  transpose_cvt<<<dim3(EMBED/32, EMBED/32), 256, 0, stream>>>(W2,   W2T, EMBED, EMBED);
  transpose_cvt<<<dim3(VPAD2/32, EMBED/32), 256, 0, stream>>>(Wout, WOT, EMBED, VOCAB);

  gemm_bt<0><<<dim3(EMBED/128, MROWS/128), 256, 0, stream>>>(XB, W1T, b1, H1, XDIM,  EMBED);
  gemm_bt<0><<<dim3(EMBED/128, MROWS/128), 256, 0, stream>>>(H1, W2T, b2, H2, EMBED, EMBED);

  gemm256<<<NWG, 512, 98304, stream>>>(H2, WOT, bout, out);
}

// Round 18
// 772.649 us; speedup vs baseline: 1.0923x; 1.0309x over previous
//
#include <hip/hip_runtime.h>
#include <hip/hip_bf16.h>

// Problem constants (fixed by reference)
#define SEQ    2048
#define BATCH  2
#define MROWS  (SEQ*BATCH)    // 4096
#define EMBED  1024
#define KCTX   3
#define XDIM   (KCTX*EMBED)   // 3072
#define VOCAB  50257
#define VPAD2  50432          // Wout^T rows allocated (zero tail: no row clamps)
#define GK     1024           // K of the logits GEMM
#define NBLKN  197            // ceil(VOCAB/256)
#define NWG    (16*NBLKN)     // 3152 blocks, divisible by 8

using u16 = unsigned short;
typedef __attribute__((ext_vector_type(8))) short   frag_ab;  // 8 bf16
typedef __attribute__((ext_vector_type(4))) float   frag_cd;  // 4 f32

__device__ __forceinline__ u16 f2bf(float f) {
  union { float f; unsigned u; } v; v.f = f;
  unsigned r = v.u + 0x7fffu + ((v.u >> 16) & 1u);
  return (u16)(r >> 16);
}

__device__ __forceinline__ void gload16(const u16* g, const u16* l) {
  __builtin_amdgcn_global_load_lds((const __attribute__((address_space(1))) void*)g,
                                   (__attribute__((address_space(3))) void*)l, 16, 0, 0);
}

// ---------------------------------------------------------------------------
// Gather: XB[r][i*1024+c] = bf16(E[tok(r,i)][c]); r = s*BATCH+b
// ---------------------------------------------------------------------------
__global__ void gather_x(const int* __restrict__ tokens,
                         const float* __restrict__ E,
                         u16* __restrict__ XB) {
  const int r = blockIdx.x;
  const int s = r >> 1, b = r & 1;
  #pragma unroll
  for (int i = 0; i < KCTX; ++i) {
    int t = s + i - (KCTX - 1);
    int tok = (t >= 0) ? tokens[t * BATCH + b] : 0;
    const float* src = &E[(size_t)tok * EMBED];
    u16* dst = &XB[(size_t)r * XDIM + i * EMBED];
    int c = threadIdx.x * 4;
    float4 v = *(const float4*)&src[c];
    u16 o[4] = { f2bf(v.x), f2bf(v.y), f2bf(v.z), f2bf(v.w) };
    *(ulong1*)&dst[c] = *(ulong1*)o;
  }
}

// ---------------------------------------------------------------------------
// Transpose + f32->bf16: W (K x N) -> WT (Npad x K). n >= N writes 0.
// ---------------------------------------------------------------------------
__global__ void transpose_cvt(const float* __restrict__ W,
                              u16* __restrict__ WT,
                              int K, int N) {
  __shared__ float tile[32][33];
  const int nb = blockIdx.x * 32, kb = blockIdx.y * 32;
  const int tx = threadIdx.x & 31, ty = threadIdx.x >> 5;
  #pragma unroll
  for (int i = 0; i < 32; i += 8) {
    int k = kb + ty + i, n = nb + tx;
    tile[ty + i][tx] = (n < N) ? W[(size_t)k * N + n] : 0.f;
  }
  __syncthreads();
  #pragma unroll
  for (int i = 0; i < 32; i += 8) {
    int n = nb + ty + i, k = kb + tx;
    WT[(size_t)n * K + k] = f2bf(tile[tx][ty + i]);
  }
}

// ---------------------------------------------------------------------------
// 128x128-tile GEMM for the two small GEMMs (r14 version: XOR bank swizzle).
// ---------------------------------------------------------------------------
template<int EPI>
__global__ __launch_bounds__(256, 2)
void gemm_bt(const u16* __restrict__ A, const u16* __restrict__ BT,
             const float* __restrict__ bias, void* __restrict__ Cout,
             int K, int Nout) {
  __shared__ u16 lA[128 * 64];
  __shared__ u16 lB[128 * 64];
  const int tid  = threadIdx.x;
  const int wave = tid >> 6, lane = tid & 63;
  const int m0 = blockIdx.y * 128;
  const int n0 = blockIdx.x * 128;
  const int wm = (wave >> 1) * 64;
  const int wn = (wave & 1) * 64;

  frag_cd acc[4][4];
  #pragma unroll
  for (int i = 0; i < 4; ++i)
    #pragma unroll
    for (int j = 0; j < 4; ++j)
      acc[i][j] = (frag_cd)0.f;

  const int srow = lane >> 3;                      // 0..7 (== row&7)
  const int skc  = ((lane & 7) ^ srow) * 8;        // pre-swizzled k slot

  for (int k0 = 0; k0 < K; k0 += 64) {
    #pragma unroll
    for (int i = 0; i < 4; ++i) {
      int chunk = wave * 4 + i;
      int r = chunk * 8 + srow;
      const u16* ga = &A [(size_t)(m0 + r) * K + k0 + skc];
      const u16* gb = &BT[(size_t)(n0 + r) * K + k0 + skc];
      gload16(ga, &lA[chunk * 512 + lane * 8]);
      gload16(gb, &lB[chunk * 512 + lane * 8]);
    }
    __syncthreads();

    #pragma unroll
    for (int kk = 0; kk < 2; ++kk) {
      const int c15 = lane & 15;
      const int s   = kk * 4 + (lane >> 4);
      const int ko  = (s ^ (c15 & 7)) * 8;         // swizzled read slot
      frag_ab af[4], bfr[4];
      #pragma unroll
      for (int i = 0; i < 4; ++i) {
        af[i]  = *(const frag_ab*)&lA[(wm + i * 16 + c15) * 64 + ko];
        bfr[i] = *(const frag_ab*)&lB[(wn + i * 16 + c15) * 64 + ko];
      }
      #pragma unroll
      for (int i = 0; i < 4; ++i)
        #pragma unroll
        for (int j = 0; j < 4; ++j)
          acc[i][j] = __builtin_amdgcn_mfma_f32_16x16x32_bf16(
              af[i], bfr[j], acc[i][j], 0, 0, 0);
    }
    __syncthreads();
  }

  const int cr = (lane >> 4) * 4;
  const int cc = lane & 15;
  if (EPI == 0) {
    u16* H = (u16*)Cout;
    #pragma unroll
    for (int j = 0; j < 4; ++j) {
      int colg = n0 + wn + j * 16 + cc;
      float bv = bias[colg];
      #pragma unroll
      for (int i = 0; i < 4; ++i)
        #pragma unroll
        for (int t = 0; t < 4; ++t) {
          int rowg = m0 + wm + i * 16 + cr + t;
          float v = acc[i][j][t] + bv;
          v = v / (1.f + __expf(-v));
          H[(size_t)rowg * Nout + colg] = f2bf(v);
        }
    }
  } else {
    float* O = (float*)Cout;
    #pragma unroll
    for (int j = 0; j < 4; ++j) {
      int colg = n0 + wn + j * 16 + cc;
      if (colg < Nout) {
        float bv = bias[colg];
        #pragma unroll
        for (int i = 0; i < 4; ++i)
          #pragma unroll
          for (int t = 0; t < 4; ++t) {
            int rowg = m0 + wm + i * 16 + cr + t;
            O[(size_t)rowg * Nout + colg] = acc[i][j][t] + bv;
          }
      }
    }
  }
}

// ---------------------------------------------------------------------------
// Logits GEMM, round 18: gemm_bk64 adopted as the real kernel.
// 256x256 tile, BK=64 windows, 2 parities x 64 KiB, ONE vmcnt(0)+barrier per
// 64-K window (half the resyncs of r9's BK=32), stage issued at window start
// and drained a full window (~1300 cyc MFMA) later. r12 inference: ~480-540us
// vs champion 588. Layout verified: row r at r*128 B, LDS slot s = global
// slot s^(r&7); reads sw0=(q^(c&7))*16 (half 0), sw1 (half 1); lgkm gates
// 7-k per the 12-read/5-needed ledger; full-line LDS epilogue (r9 path).
// ---------------------------------------------------------------------------
#define BARR   asm volatile("s_barrier" ::: "memory")
#define VMCNT0 asm volatile("s_waitcnt vmcnt(0)" ::: "memory")
#define LGKMC(N) asm volatile("s_waitcnt lgkmcnt(" #N ")" ::: "memory")
#define SCHED0 __builtin_amdgcn_sched_barrier(0)
#define PRIO1  __builtin_amdgcn_s_setprio(1)
#define PRIO0  __builtin_amdgcn_s_setprio(0)
#define DSREAD(DST, AREG, IMM) \
  asm volatile("ds_read_b128 %0, %1 offset:%2" : "=v"(DST) : "v"(AREG), "i"(IMM))
#define MFMA4(MF) { \
  _Pragma("unroll") for (int nf = 0; nf < 4; ++nf) \
    acc[MF][nf] = __builtin_amdgcn_mfma_f32_16x16x32_bf16(hF[MF], wF[nf], acc[MF][nf], 0, 0, 0); }

#define BSTAGE(WP) { \
  gload16(pa,          (const u16*)(smraw + (WP)         + stoffB)); \
  gload16(pa +  65536, (const u16*)(smraw + (WP) +  8192 + stoffB)); \
  gload16(pa + 131072, (const u16*)(smraw + (WP) + 16384 + stoffB)); \
  gload16(pa + 196608, (const u16*)(smraw + (WP) + 24576 + stoffB)); \
  gload16(pb,          (const u16*)(smraw + (WP) + 32768 + stoffB)); \
  gload16(pb +  65536, (const u16*)(smraw + (WP) + 40960 + stoffB)); \
  gload16(pb + 131072, (const u16*)(smraw + (WP) + 49152 + stoffB)); \
  gload16(pb + 196608, (const u16*)(smraw + (WP) + 57344 + stoffB)); \
  pa += 64; pb += 64; }

#define BRD(REGW, REGH) { \
  DSREAD(wF[0], REGW, 0*2048); \
  DSREAD(wF[1], REGW, 1*2048); \
  DSREAD(wF[2], REGW, 2*2048); \
  DSREAD(wF[3], REGW, 3*2048); \
  DSREAD(hF[0], REGH, 0*2048); \
  DSREAD(hF[1], REGH, 1*2048); \
  DSREAD(hF[2], REGH, 2*2048); \
  DSREAD(hF[3], REGH, 3*2048); \
  DSREAD(hF[4], REGH, 4*2048); \
  DSREAD(hF[5], REGH, 5*2048); \
  DSREAD(hF[6], REGH, 6*2048); \
  DSREAD(hF[7], REGH, 7*2048); }

#define GROUPS8 { \
  PRIO1; \
  LGKMC(7); SCHED0; MFMA4(0); \
  LGKMC(6); SCHED0; MFMA4(1); \
  LGKMC(5); SCHED0; MFMA4(2); \
  LGKMC(4); SCHED0; MFMA4(3); \
  LGKMC(3); SCHED0; MFMA4(4); \
  LGKMC(2); SCHED0; MFMA4(5); \
  LGKMC(1); SCHED0; MFMA4(6); \
  LGKMC(0); SCHED0; MFMA4(7); \
  PRIO0; SCHED0; }

#define BWIN(RW0, RH0, RW1, RH1, WP) { \
  VMCNT0; BARR; \
  BSTAGE(WP); \
  BRD(RW0, RH0); \
  GROUPS8; \
  BRD(RW1, RH1); \
  GROUPS8; }

__global__ __launch_bounds__(512, 2)
void gemm_bk64(const u16* __restrict__ A, const u16* __restrict__ BT,
               const float* __restrict__ bias, float* __restrict__ O) {
  extern __shared__ char smraw[];

  // Bijective chunked XCD swizzle; M-innermost so one XCD reuses one B-panel.
  const int bid = blockIdx.x;
  const int wg  = (bid & 7) * (NWG / 8) + (bid >> 3);
  const int m0  = (wg & 15) * 256;
  const int n0  = (wg >> 4) * 256;

  const int tid  = threadIdx.x;
  const int lane = tid & 63, wave = tid >> 6;
  const int wm = wave >> 2, wn = wave & 3;

  // staging: 8 chunks of 64 rows x 8 slots; dest linear = chunkbase + tid*16
  const int stoffB = tid * 16;
  const int r8 = tid >> 3, slot = tid & 7;
  const int ke = ((slot ^ (r8 & 7)) * 8);
  const u16* pa = A  + (size_t)(m0 + r8) * GK + ke;
  const u16* pb = BT + (size_t)(n0 + r8) * GK + ke;   // VPAD2 rows: no clamp

  // ds_read base regs: row stride 128 B; slot swizzle ^ (row&7), per k-half;
  // parity-1 bases are separate registers (+65536 B; 16-bit ds imm limit).
  const unsigned dynbase = (unsigned)(size_t)(__attribute__((address_space(3))) char*)smraw;
  const int c = lane & 15, q = lane >> 4;
  const unsigned sw0 = (unsigned)(((q    ) ^ (c & 7)) * 16);
  const unsigned sw1 = (unsigned)(((q + 4) ^ (c & 7)) * 16);
  const unsigned regH_h0_p0 = dynbase + (unsigned)((wm * 128 + c) * 128) + sw0;
  const unsigned regH_h1_p0 = dynbase + (unsigned)((wm * 128 + c) * 128) + sw1;
  const unsigned regW_h0_p0 = dynbase + 32768u + (unsigned)((wn * 64 + c) * 128) + sw0;
  const unsigned regW_h1_p0 = dynbase + 32768u + (unsigned)((wn * 64 + c) * 128) + sw1;
  const unsigned regH_h0_p1 = regH_h0_p0 + 65536u;
  const unsigned regH_h1_p1 = regH_h1_p0 + 65536u;
  const unsigned regW_h0_p1 = regW_h0_p0 + 65536u;
  const unsigned regW_h1_p1 = regW_h1_p0 + 65536u;

  frag_ab hF[8], wF[4];
  frag_cd acc[8][4];
  #pragma unroll
  for (int i = 0; i < 8; ++i)
    #pragma unroll
    for (int j = 0; j < 4; ++j)
      acc[i][j] = (frag_cd)0.f;

  BSTAGE(0);   // window 0 -> parity 0

  #pragma unroll 1
  for (int w = 0; w < 8; ++w) {
    BWIN(regW_h0_p0, regH_h0_p0, regW_h1_p0, regH_h1_p0, 65536);  // read p0, stage p1
    BWIN(regW_h0_p1, regH_h0_p1, regW_h1_p1, regH_h1_p1, 0);      // read p1, stage p0
  }
  // (last window staged from k=1024: harmless in-workspace over-read)

  asm volatile("s_waitcnt vmcnt(0) lgkmcnt(0)" ::: "memory");
  BARR;

  // epilogue: full-128B-line store path (r9-verified)
  float* lfs = (float*)smraw;
  const int colg = n0 + wn * 64 + c * 4;
  #pragma unroll
  for (int mf = 0; mf < 8; ++mf) {
    const int lbase = wave * 1088 + (mf & 1) * 8704;
    #pragma unroll
    for (int nf = 0; nf < 4; ++nf)
      #pragma unroll
      for (int t = 0; t < 4; ++t)
        lfs[lbase + (q * 4 + t) * 68 + nf * 16 + c] = acc[mf][nf][t];
    #pragma unroll
    for (int p = 0; p < 4; ++p) {
      frag_cd v = *(const frag_cd*)&lfs[lbase + (p * 4 + q) * 68 + c * 4];
      const int rowg = m0 + wm * 128 + mf * 16 + p * 4 + q;
      if (colg + 3 < VOCAB) {
        frag_cd bv = *(const frag_cd*)&bias[colg];
        v += bv;
        *(frag_cd*)&O[(size_t)rowg * VOCAB + colg] = v;
      } else {
        #pragma unroll
        for (int t = 0; t < 4; ++t)
          if (colg + t < VOCAB)
            O[(size_t)rowg * VOCAB + colg + t] = v[t] + bias[colg + t];
      }
    }
  }
}

// ---------------------------------------------------------------------------
extern "C" void kernel_launch(void* const* d_in, const int* in_sizes, int n_in,
                              void* d_out, int out_size, void* d_ws, size_t ws_size,
                              hipStream_t stream) {
  const int*   tokens = (const int*)  d_in[0];
  const float* E      = (const float*)d_in[1];
  const float* W1     = (const float*)d_in[2];
  const float* b1     = (const float*)d_in[3];
  const float* W2     = (const float*)d_in[4];
  const float* b2     = (const float*)d_in[5];
  const float* Wout   = (const float*)d_in[6];
  const float* bout   = (const float*)d_in[7];
  float* out = (float*)d_out;

  // Workspace layout (~153.7 MB); K-loop over-advance reads land inside ws
  // (WOT -> H1, H2 -> W1T).
  char* p = (char*)d_ws;
  u16* XB  = (u16*)p; p += (size_t)MROWS * XDIM  * 2;   // 25.2 MB
  u16* WOT = (u16*)p; p += (size_t)VPAD2 * EMBED * 2;   // 103.3 MB
  u16* H1  = (u16*)p; p += (size_t)MROWS * EMBED * 2;   //  8.4 MB
  u16* H2  = (u16*)p; p += (size_t)MROWS * EMBED * 2;   //  8.4 MB
  u16* W1T = (u16*)p; p += (size_t)EMBED * XDIM  * 2;   //  6.3 MB
  u16* W2T = (u16*)p; p += (size_t)EMBED * EMBED * 2;   //  2.1 MB

  hipFuncSetAttribute((const void*)gemm_bk64,
                      hipFuncAttributeMaxDynamicSharedMemorySize, 131072);

  gather_x<<<MROWS, 256, 0, stream>>>(tokens, E, XB);
  transpose_cvt<<<dim3(EMBED/32, XDIM/32),  256, 0, stream>>>(W1,   W1T, XDIM,  EMBED);
  transpose_cvt<<<dim3(EMBED/32, EMBED/32), 256, 0, stream>>>(W2,   W2T, EMBED, EMBED);
  transpose_cvt<<<dim3(VPAD2/32, EMBED/32), 256, 0, stream>>>(Wout, WOT, EMBED, VOCAB);

  gemm_bt<0><<<dim3(EMBED/128, MROWS/128), 256, 0, stream>>>(XB, W1T, b1, H1, XDIM,  EMBED);
  gemm_bt<0><<<dim3(EMBED/128, MROWS/128), 256, 0, stream>>>(H1, W2T, b2, H2, EMBED, EMBED);

  gemm_bk64<<<NWG, 512, 131072, stream>>>(H2, WOT, bout, out);
}